// Round 8
// baseline (81.744 us; speedup 1.0000x reference)
//
#include <hip/hip_runtime.h>

// PixelVectorExtractor: one transformer encoder layer over per-pixel 7x7
// windows in a 30x30 canvas (S=900, D=11).
//  - only 49/900 rows nonzero; 851 zero rows share ONE output vector.
//  - zero-score keys: +851 to softmax denom, nothing to numerator.
// R7 post-mortem: rows kernel ~13-15us with ONE 9-wave barrier domain per CU
// (grid 256 == CU count): every __syncthreads stalls the whole CU.
// v8: HALF-PIXEL BLOCKS. grid=512, TPB=320 (5 waves): block bp handles
// pixel bp>>1, rows (bp&1)*25..+25. K/V for all 49 rows are (cheaply)
// duplicated per half-block; phases 2-8 run on 25 rows. 2 blocks/CU = two
// independent barrier domains that fill each other's drains.
// Kernel B (broadcast write of the 9.2MB output from the 532KB row table)
// unchanged from R7.

#define D 11
#define ROWP 12      // padded row length (3 x float4), pads = 0
#define NW 49
#define NWP 52       // padded score-row length (13 x float4), pads = 0
#define NR 50
#define SEQ 900
#define FFD 64
#define CIN 10
#define RPB 25       // rows per half-block
#define GRID_A 512
#define TPB 320
#define NRD (NR * D)    // 550
#define NWD (NW * D)    // 539
#define RPD (RPB * D)   // 275
#define TROW 52         // T row stride (floats) per (b,c)

__device__ __forceinline__ float dot12(const float4* a, const float4* b) {
    float4 s = make_float4(0.f, 0.f, 0.f, 0.f);
    #pragma unroll
    for (int i = 0; i < 3; ++i) {
        float4 x = a[i], y = b[i];
        s.x += x.x * y.x; s.y += x.y * y.y; s.z += x.z * y.z; s.w += x.w * y.w;
    }
    return s.x + s.y + s.z + s.w;
}

__global__ __launch_bounds__(TPB) void pve_rows(
    const float* __restrict__ gx,     // [10,16,16]
    const float* __restrict__ gWqkv,  // [33,11]
    const float* __restrict__ gWo,    // [11,11]
    const float* __restrict__ gW1,    // [64,11]
    const float* __restrict__ gW2,    // [11,64]
    const float* __restrict__ gln1,   // [11]
    const float* __restrict__ gln2,   // [11]
    float* __restrict__ T)            // [256,10,52] row table
{
    __shared__ __align__(16) float sQ[33 * ROWP];    // Wqkv rows, padded
    __shared__ __align__(16) float sWo[D * ROWP];
    __shared__ __align__(16) float sW1[FFD * ROWP];
    __shared__ __align__(16) float sW2[D * FFD];     // rows of 64
    __shared__ float sln1[D], sln2[D];
    __shared__ __align__(16) float sSeq[NR][ROWP];   // all 50 rows (for K/V)
    __shared__ __align__(16) float sK[NW][ROWP];
    __shared__ __align__(16) float sVt[D][NWP];      // V transposed, [d][t]
    // per-half-block (25 own rows):
    __shared__ __align__(16) float sQr[RPB][ROWP];
    __shared__ __align__(16) float sE[RPB][NWP];     // exp(scores), pads = 0
    __shared__ __align__(16) float sNum[RPB][ROWP];
    __shared__ float sDen[RPB];
    __shared__ __align__(16) float sX1[RPB][ROWP];
    __shared__ __align__(16) float sX1n[RPB][ROWP];
    __shared__ __align__(16) float sH[RPB][FFD];
    __shared__ __align__(16) float sY[RPB][ROWP];

    const int tid = threadIdx.x;
    const int bp = blockIdx.x;
    const int b = bp >> 1;            // pixel
    const int row0 = (bp & 1) * RPB;  // first own row (0 or 25)
    const int h = b >> 4;
    const int w = b & 15;

    // ---- phase 0: stage weights (zero-padded rows) + seq for ALL 50 rows ----
    for (int i = tid; i < 33 * ROWP; i += TPB) {
        const int rr = i / ROWP, cc = i - rr * ROWP;
        sQ[i] = (cc < D) ? gWqkv[rr * D + cc] : 0.f;
    }
    for (int i = tid; i < D * ROWP; i += TPB) {
        const int rr = i / ROWP, cc = i - rr * ROWP;
        sWo[i] = (cc < D) ? gWo[rr * D + cc] : 0.f;
    }
    for (int i = tid; i < FFD * ROWP; i += TPB) {
        const int rr = i / ROWP, cc = i - rr * ROWP;
        sW1[i] = (cc < D) ? gW1[rr * D + cc] : 0.f;
    }
    for (int i = tid; i < D * FFD; i += TPB) sW2[i] = gW2[i];
    if (tid < D) { sln1[tid] = gln1[tid]; sln2[tid] = gln2[tid]; }

    #pragma unroll
    for (int k = 0; k < 2; ++k) {
        const int idx = tid + k * TPB;
        if (idx < NRD) {
            const int r = idx / D;
            const int d = idx - r * D;
            float val = 0.0f;
            if (r < NW) {
                const int i = r / 7, j = r - (r / 7) * 7;
                const int y = h + i, xx = w + j;
                const bool inter = (y >= 3) && (y < 19) && (xx >= 3) && (xx < 19);
                const int base = inter ? ((y - 3) * 16 + (xx - 3)) : 0;
                if (d < CIN) val = inter ? gx[d * 256 + base] : 0.0f;
                else         val = inter ? 0.0f : 1.0f;   // mask channel
            }
            sSeq[r][d] = val;
            if (d == CIN) sSeq[r][D] = 0.f;               // row pad
        }
    }
    __syncthreads();

    // ---- phase 1: K,V for all 49 rows; q for OWN 25 rows; sVt pads ----
    #pragma unroll
    for (int k = 0; k < 2; ++k) {
        const int idx = tid + k * TPB;
        if (idx < NWD) {
            const int t = idx / D;
            const int d = idx - t * D;
            const float4* sv = (const float4*)&sSeq[t][0];
            const float ak = dot12(sv, (const float4*)&sQ[(D + d) * ROWP]);
            const float av = dot12(sv, (const float4*)&sQ[(2 * D + d) * ROWP]);
            sK[t][d] = ak;
            if (d == CIN) sK[t][D] = 0.f;
            sVt[d][t] = av;
        }
    }
    if (tid < RPD) {
        const int rl = tid / D;
        const int d = tid - rl * D;
        const int r = row0 + rl;                 // r==49 is the zero row
        const float aq = dot12((const float4*)&sSeq[r][0],
                               (const float4*)&sQ[d * ROWP]);
        sQr[rl][d] = aq;
        if (d == CIN) sQr[rl][D] = 0.f;
    } else if (tid < RPD + D * 3) {              // sVt pad cols 49..51 = 0
        const int p = tid - RPD;
        sVt[p / 3][NW + (p % 3)] = 0.f;
    }
    __syncthreads();

    // ---- phase 2: scores + exp for own rows over padded 25x52 grid ----
    {
        const float scale = 0.30151134457776363f;   // 1/sqrt(11)
        #pragma unroll
        for (int k = 0; k < 5; ++k) {
            const int idx = tid + k * TPB;
            if (idx < RPB * NWP) {
                const int rl = idx / NWP;
                const int tt = idx - rl * NWP;
                float e = 0.f;
                if (tt < NW) {
                    const float s = dot12((const float4*)&sQr[rl][0],
                                          (const float4*)&sK[tt][0]);
                    e = __expf(s * scale);
                }
                sE[rl][tt] = e;                     // pads get exactly 0
            }
        }
    }
    __syncthreads();

    // ---- phase 3: softmax numerator (and denom on d==0 lanes) ----
    if (tid < RPD) {
        const int rl = tid / D;
        const int d = tid - rl * D;
        const float4* ev = (const float4*)&sE[rl][0];
        const float4* vv = (const float4*)&sVt[d][0];
        float4 an = make_float4(0.f, 0.f, 0.f, 0.f);
        float4 ad = make_float4(0.f, 0.f, 0.f, 0.f);
        #pragma unroll
        for (int i = 0; i < 13; ++i) {
            const float4 e = ev[i], v = vv[i];
            an.x += e.x * v.x; an.y += e.y * v.y;
            an.z += e.z * v.z; an.w += e.w * v.w;
            ad.x += e.x; ad.y += e.y; ad.z += e.z; ad.w += e.w;
        }
        sNum[rl][d] = an.x + an.y + an.z + an.w;
        if (d == CIN) sNum[rl][D] = 0.f;
        if (d == 0) sDen[rl] = 851.0f + ad.x + ad.y + ad.z + ad.w;
    }
    __syncthreads();

    // ---- phase 4: out-proj + residual ----
    if (tid < RPD) {
        const int rl = tid / D;
        const int d = tid - rl * D;
        const float acc = dot12((const float4*)&sNum[rl][0],
                                (const float4*)&sWo[d * ROWP]);
        sX1[rl][d] = sSeq[row0 + rl][d] + acc / sDen[rl];
        if (d == CIN) sX1[rl][D] = 0.f;
    }
    __syncthreads();

    // ---- phase 5: LN1 (pads are 0; raw-moment form) ----
    if (tid < RPD) {
        const int rl = tid / D;
        const int d = tid - rl * D;
        const float4* xv = (const float4*)&sX1[rl][0];
        float4 s4 = make_float4(0.f, 0.f, 0.f, 0.f);
        float4 q4 = make_float4(0.f, 0.f, 0.f, 0.f);
        #pragma unroll
        for (int i = 0; i < 3; ++i) {
            const float4 x = xv[i];
            s4.x += x.x; s4.y += x.y; s4.z += x.z; s4.w += x.w;
            q4.x += x.x * x.x; q4.y += x.y * x.y;
            q4.z += x.z * x.z; q4.w += x.w * x.w;
        }
        const float sum = s4.x + s4.y + s4.z + s4.w;
        const float sq  = q4.x + q4.y + q4.z + q4.w;
        const float m   = sum * (1.0f / 11.0f);
        const float var = sq * (1.0f / 11.0f) - m * m;
        sX1n[rl][d] = (sX1[rl][d] - m) * rsqrtf(var + 1e-5f) * sln1[d];
        if (d == CIN) sX1n[rl][D] = 0.f;
    }
    __syncthreads();

    // ---- phase 6: FF hidden, 25x64 = 1600 over 320 threads ----
    #pragma unroll
    for (int k = 0; k < 5; ++k) {
        const int idx = tid + k * TPB;
        if (idx < RPB * FFD) {
            const int rl = idx >> 6;
            const int ff = idx & 63;
            const float acc = dot12((const float4*)&sX1n[rl][0],
                                    (const float4*)&sW1[ff * ROWP]);
            sH[rl][ff] = fmaxf(acc, 0.0f);
        }
    }
    __syncthreads();

    // ---- phase 7: FF out + residual (contiguous over f) ----
    if (tid < RPD) {
        const int rl = tid / D;
        const int d = tid - rl * D;
        const float4* hv = (const float4*)&sH[rl][0];
        const float4* wv = (const float4*)&sW2[d * FFD];
        float4 a4 = make_float4(0.f, 0.f, 0.f, 0.f);
        #pragma unroll
        for (int i = 0; i < 16; ++i) {
            const float4 hh = hv[i], ww = wv[i];
            a4.x += hh.x * ww.x; a4.y += hh.y * ww.y;
            a4.z += hh.z * ww.z; a4.w += hh.w * ww.w;
        }
        sY[rl][d] = sX1n[rl][d] + a4.x + a4.y + a4.z + a4.w;
        if (d == CIN) sY[rl][D] = 0.f;
    }
    __syncthreads();

    // ---- phase 8: LN2 + direct store of own rows to T ----
    if (tid < RPD) {
        const int rl = tid / D;
        const int d = tid - rl * D;
        const float4* yv = (const float4*)&sY[rl][0];
        float4 s4 = make_float4(0.f, 0.f, 0.f, 0.f);
        float4 q4 = make_float4(0.f, 0.f, 0.f, 0.f);
        #pragma unroll
        for (int i = 0; i < 3; ++i) {
            const float4 y = yv[i];
            s4.x += y.x; s4.y += y.y; s4.z += y.z; s4.w += y.w;
            q4.x += y.x * y.x; q4.y += y.y * y.y;
            q4.z += y.z * y.z; q4.w += y.w * y.w;
        }
        const float sum = s4.x + s4.y + s4.z + s4.w;
        const float sq  = q4.x + q4.y + q4.z + q4.w;
        const float m   = sum * (1.0f / 11.0f);
        const float var = sq * (1.0f / 11.0f) - m * m;
        const float val = (sY[rl][d] - m) * rsqrtf(var + 1e-5f) * sln2[d];
        if (d < CIN)                       // mask channel (d==10) dropped
            T[(b * CIN + d) * TROW + row0 + rl] = val;
    }
}

// Kernel B: pure broadcast write. One float4 per thread; 2250 blocks x 256.
__global__ __launch_bounds__(256) void pve_write(
    const float* __restrict__ T,      // [256,10,52]
    float4* __restrict__ out4)        // [256*10*900/4]
{
    const int flat = blockIdx.x * 256 + threadIdx.x;   // < 576000
    const int b   = flat / 2250;
    const int rem = flat - b * 2250;
    const int c   = rem / 225;                         // 225 float4 / channel
    const int s0  = (rem - c * 225) * 4;
    const float* tb = T + (b * CIN + c) * TROW;
    float4 v4;
    float* pv = (float*)&v4;
    #pragma unroll
    for (int u = 0; u < 4; ++u) {
        const int s = s0 + u;
        const int i = s / 30;
        const int j = s - i * 30;
        const int row = (i < 7 && j < 7) ? (i * 7 + j) : NW;   // 49 = zero row
        pv[u] = tb[row];
    }
    out4[flat] = v4;
}

extern "C" void kernel_launch(void* const* d_in, const int* in_sizes, int n_in,
                              void* d_out, int out_size, void* d_ws, size_t ws_size,
                              hipStream_t stream) {
    (void)in_sizes; (void)n_in; (void)out_size; (void)ws_size;
    const float* x    = (const float*)d_in[0];
    const float* Wqkv = (const float*)d_in[1];
    const float* Wo   = (const float*)d_in[2];
    const float* W1   = (const float*)d_in[3];
    const float* W2   = (const float*)d_in[4];
    const float* ln1  = (const float*)d_in[5];
    const float* ln2  = (const float*)d_in[6];
    float* T = (float*)d_ws;          // 256*10*52 floats = 532 KB
    pve_rows<<<GRID_A, TPB, 0, stream>>>(x, Wqkv, Wo, W1, W2, ln1, ln2, T);
    pve_write<<<576000 / 256, 256, 0, stream>>>(T, (float4*)d_out);
}

// Round 9
// 80.427 us; speedup vs baseline: 1.0164x; 1.0164x over previous
//
#include <hip/hip_runtime.h>

// PixelVectorExtractor: one transformer encoder layer over per-pixel 7x7
// windows in a 30x30 canvas (S=900, D=11). Structure exploited:
//  - only 49/900 rows nonzero; 851 zero rows share ONE output vector.
//  - zero-score keys: +851 to softmax denom, nothing to numerator.
//
// R8 post-mortem / consolidation: four structural variants (R4/R5/R7/R8)
// all land at bench 79.7-81.7 despite 4x LDS-instruction and 2x barrier-
// domain differences -> residual time is dispatch/launch floor + harness
// const + ~1.5us HBM write, not in-kernel throughput. This is the empirical
// argmin config: R5's single-kernel 576-thread phase structure (9 waves/CU,
// float4 LDS everywhere, fused epilogue; ONE dispatch).

#define D 11
#define ROWP 12      // padded row length (3 x float4), pad element = 0
#define NW 49
#define NWP 52       // padded score-row length (13 x float4), pads = 0
#define NR 50
#define SEQ 900
#define FFD 64
#define CIN 10
#define NB 256
#define TPB 576
#define NRD (NR * D)  // 550

__device__ __forceinline__ float dot12(const float4* a, const float4* b) {
    float4 s = make_float4(0.f, 0.f, 0.f, 0.f);
    #pragma unroll
    for (int i = 0; i < 3; ++i) {
        float4 x = a[i], y = b[i];
        s.x += x.x * y.x; s.y += x.y * y.y; s.z += x.z * y.z; s.w += x.w * y.w;
    }
    return s.x + s.y + s.z + s.w;
}

__global__ __launch_bounds__(TPB) void pve_kernel(
    const float* __restrict__ gx,     // [10,16,16]
    const float* __restrict__ gWqkv,  // [33,11]
    const float* __restrict__ gWo,    // [11,11]
    const float* __restrict__ gW1,    // [64,11]
    const float* __restrict__ gW2,    // [11,64]
    const float* __restrict__ gln1,   // [11]
    const float* __restrict__ gln2,   // [11]
    float* __restrict__ out)          // [256,10,900]
{
    __shared__ __align__(16) float sQ[33 * ROWP];    // Wqkv rows, padded
    __shared__ __align__(16) float sWo[D * ROWP];
    __shared__ __align__(16) float sW1[FFD * ROWP];
    __shared__ __align__(16) float sW2[D * FFD];     // rows of 64, contiguous
    __shared__ float sln1[D], sln2[D];
    __shared__ __align__(16) float sSeq[NR][ROWP];
    __shared__ __align__(16) float sK[NW][ROWP];
    __shared__ __align__(16) float sVt[D][NWP];      // V transposed, [d][t]
    __shared__ __align__(16) float sQr[NR][ROWP];
    __shared__ __align__(16) float sE[NR][NWP];      // exp(scores), pads = 0
    __shared__ __align__(16) float sNum[NR][ROWP];
    __shared__ float sDen[NR];
    __shared__ __align__(16) float sX1[NR][ROWP];
    __shared__ __align__(16) float sX1n[NR][ROWP];
    __shared__ __align__(16) float sH[NR][FFD];
    __shared__ __align__(16) float sY[NR][ROWP];
    __shared__ __align__(16) float sR[NR][ROWP];

    const int tid = threadIdx.x;
    const int b = blockIdx.x;
    const int h = b >> 4;
    const int w = b & 15;

    const int rd = tid;               // (r,d), valid when < 550
    const int r = rd / D;
    const int d = rd - r * D;

    // ---- phase 0: stage weights (zero-padded rows) + build seq rows ----
    for (int i = tid; i < 33 * ROWP; i += TPB) {
        const int rr = i / ROWP, cc = i - rr * ROWP;
        sQ[i] = (cc < D) ? gWqkv[rr * D + cc] : 0.f;
    }
    for (int i = tid; i < D * ROWP; i += TPB) {
        const int rr = i / ROWP, cc = i - rr * ROWP;
        sWo[i] = (cc < D) ? gWo[rr * D + cc] : 0.f;
    }
    for (int i = tid; i < FFD * ROWP; i += TPB) {
        const int rr = i / ROWP, cc = i - rr * ROWP;
        sW1[i] = (cc < D) ? gW1[rr * D + cc] : 0.f;
    }
    for (int i = tid; i < D * FFD; i += TPB) sW2[i] = gW2[i];
    if (tid < D) { sln1[tid] = gln1[tid]; sln2[tid] = gln2[tid]; }

    if (rd < NRD) {
        float val = 0.0f;
        if (r < NW) {
            const int i = r / 7, j = r - (r / 7) * 7;
            const int y = h + i, xx = w + j;
            const bool inter = (y >= 3) && (y < 19) && (xx >= 3) && (xx < 19);
            const int base = inter ? ((y - 3) * 16 + (xx - 3)) : 0;
            if (d < CIN) val = inter ? gx[d * 256 + base] : 0.0f;
            else         val = inter ? 0.0f : 1.0f;     // mask channel
        }
        sSeq[r][d] = val;
        if (d == CIN) sSeq[r][D] = 0.f;                 // row pad
    }
    __syncthreads();

    // ---- phase 1: qkv projection, thread=(r,d); V written transposed ----
    if (rd < NRD) {
        const float4* sv = (const float4*)&sSeq[r][0];
        const float aq = dot12(sv, (const float4*)&sQ[d * ROWP]);
        const float ak = dot12(sv, (const float4*)&sQ[(D + d) * ROWP]);
        const float av = dot12(sv, (const float4*)&sQ[(2 * D + d) * ROWP]);
        sQr[r][d] = aq;
        if (d == CIN) sQr[r][D] = 0.f;
        if (r < NW) { sK[r][d] = ak; sVt[d][r] = av;
                      if (d == CIN) sK[r][D] = 0.f; }
        else { sVt[d][NW] = 0.f; sVt[d][NW + 1] = 0.f; sVt[d][NW + 2] = 0.f; }
    }
    __syncthreads();

    // ---- phase 2: scores + exp over padded 50x52 grid ----
    {
        const float scale = 0.30151134457776363f;   // 1/sqrt(11)
        #pragma unroll
        for (int k = 0; k < 5; ++k) {
            const int idx = tid + k * TPB;
            if (idx < NR * NWP) {
                const int rr = idx / NWP;
                const int tt = idx - rr * NWP;
                float e = 0.f;
                if (tt < NW) {
                    const float s = dot12((const float4*)&sQr[rr][0],
                                          (const float4*)&sK[tt][0]);
                    e = __expf(s * scale);
                }
                sE[rr][tt] = e;                     // pads get exactly 0
            }
        }
    }
    __syncthreads();

    // ---- phase 3: softmax numerator (and denom on d==0 lanes) ----
    if (rd < NRD) {
        const float4* ev = (const float4*)&sE[r][0];
        const float4* vv = (const float4*)&sVt[d][0];
        float4 an = make_float4(0.f, 0.f, 0.f, 0.f);
        float4 ad = make_float4(0.f, 0.f, 0.f, 0.f);
        #pragma unroll
        for (int i = 0; i < 13; ++i) {
            const float4 e = ev[i], v = vv[i];
            an.x += e.x * v.x; an.y += e.y * v.y;
            an.z += e.z * v.z; an.w += e.w * v.w;
            ad.x += e.x; ad.y += e.y; ad.z += e.z; ad.w += e.w;
        }
        sNum[r][d] = an.x + an.y + an.z + an.w;
        if (d == CIN) sNum[r][D] = 0.f;
        if (d == 0) sDen[r] = 851.0f + ad.x + ad.y + ad.z + ad.w;
    }
    __syncthreads();

    // ---- phase 4: out-proj + residual ----
    if (rd < NRD) {
        const float acc = dot12((const float4*)&sNum[r][0],
                                (const float4*)&sWo[d * ROWP]);
        sX1[r][d] = sSeq[r][d] + acc / sDen[r];
        if (d == CIN) sX1[r][D] = 0.f;
    }
    __syncthreads();

    // ---- phase 5: LN1 (pads are 0; raw-moment form) ----
    if (rd < NRD) {
        const float4* xv = (const float4*)&sX1[r][0];
        float4 s4 = make_float4(0.f, 0.f, 0.f, 0.f);
        float4 q4 = make_float4(0.f, 0.f, 0.f, 0.f);
        #pragma unroll
        for (int i = 0; i < 3; ++i) {
            const float4 x = xv[i];
            s4.x += x.x; s4.y += x.y; s4.z += x.z; s4.w += x.w;
            q4.x += x.x * x.x; q4.y += x.y * x.y;
            q4.z += x.z * x.z; q4.w += x.w * x.w;
        }
        const float sum = s4.x + s4.y + s4.z + s4.w;
        const float sq  = q4.x + q4.y + q4.z + q4.w;
        const float m   = sum * (1.0f / 11.0f);
        const float var = sq * (1.0f / 11.0f) - m * m;
        sX1n[r][d] = (sX1[r][d] - m) * rsqrtf(var + 1e-5f) * sln1[d];
        if (d == CIN) sX1n[r][D] = 0.f;
    }
    __syncthreads();

    // ---- phase 6: FF hidden, 50x64 over 576 threads ----
    #pragma unroll
    for (int k = 0; k < 6; ++k) {
        const int idx = tid + k * TPB;
        if (idx < NR * FFD) {
            const int rr = idx >> 6;
            const int ff = idx & 63;
            const float acc = dot12((const float4*)&sX1n[rr][0],
                                    (const float4*)&sW1[ff * ROWP]);
            sH[rr][ff] = fmaxf(acc, 0.0f);
        }
    }
    __syncthreads();

    // ---- phase 7: FF out + residual (contiguous over f) ----
    if (rd < NRD) {
        const float4* hv = (const float4*)&sH[r][0];
        const float4* wv = (const float4*)&sW2[d * FFD];
        float4 a4 = make_float4(0.f, 0.f, 0.f, 0.f);
        #pragma unroll
        for (int i = 0; i < 16; ++i) {
            const float4 hh = hv[i], ww = wv[i];
            a4.x += hh.x * ww.x; a4.y += hh.y * ww.y;
            a4.z += hh.z * ww.z; a4.w += hh.w * ww.w;
        }
        sY[r][d] = sX1n[r][d] + a4.x + a4.y + a4.z + a4.w;
        if (d == CIN) sY[r][D] = 0.f;
    }
    __syncthreads();

    // ---- phase 8: LN2 ----
    if (rd < NRD) {
        const float4* yv = (const float4*)&sY[r][0];
        float4 s4 = make_float4(0.f, 0.f, 0.f, 0.f);
        float4 q4 = make_float4(0.f, 0.f, 0.f, 0.f);
        #pragma unroll
        for (int i = 0; i < 3; ++i) {
            const float4 y = yv[i];
            s4.x += y.x; s4.y += y.y; s4.z += y.z; s4.w += y.w;
            q4.x += y.x * y.x; q4.y += y.y * y.y;
            q4.z += y.z * y.z; q4.w += y.w * y.w;
        }
        const float sum = s4.x + s4.y + s4.z + s4.w;
        const float sq  = q4.x + q4.y + q4.z + q4.w;
        const float m   = sum * (1.0f / 11.0f);
        const float var = sq * (1.0f / 11.0f) - m * m;
        sR[r][d] = (sY[r][d] - m) * rsqrtf(var + 1e-5f) * sln2[d];
    }
    __syncthreads();

    // ---- phase 9: epilogue, out[b,c,s] as float4 (2250 per block) ----
    float4* ob4 = (float4*)(out + b * (CIN * SEQ));
    #pragma unroll
    for (int k = 0; k < 4; ++k) {
        const int qi = tid + k * TPB;
        if (qi < 2250) {
            const int c  = qi / 225;             // 225 float4 per channel
            const int s0 = (qi - c * 225) * 4;
            float4 v4;
            float* pv = (float*)&v4;
            #pragma unroll
            for (int u = 0; u < 4; ++u) {
                const int s = s0 + u;
                const int i = s / 30;
                const int j = s - i * 30;
                pv[u] = (i < 7 && j < 7) ? sR[i * 7 + j][c] : sR[NW][c];
            }
            ob4[qi] = v4;
        }
    }
}

extern "C" void kernel_launch(void* const* d_in, const int* in_sizes, int n_in,
                              void* d_out, int out_size, void* d_ws, size_t ws_size,
                              hipStream_t stream) {
    (void)in_sizes; (void)n_in; (void)out_size; (void)d_ws; (void)ws_size;
    const float* x    = (const float*)d_in[0];
    const float* Wqkv = (const float*)d_in[1];
    const float* Wo   = (const float*)d_in[2];
    const float* W1   = (const float*)d_in[3];
    const float* W2   = (const float*)d_in[4];
    const float* ln1  = (const float*)d_in[5];
    const float* ln2  = (const float*)d_in[6];
    pve_kernel<<<NB, TPB, 0, stream>>>(x, Wqkv, Wo, W1, W2, ln1, ln2,
                                       (float*)d_out);
}